// Round 6
// baseline (266.400 us; speedup 1.0000x reference)
//
#include <hip/hip_runtime.h>
#include <hip/hip_cooperative_groups.h>
#include <math.h>

namespace cg = cooperative_groups;

#define HDIM 128
#define EPSV 1e-5f
#define TOLV 1e-7f
#define MINSCORE 0.1f
#define PMAX 2048
#define GMAX 64
#define KSEG 16
#define ESEG 64
#define NB 256
#define NT 1024

struct Prm {
    const float *x; const int *src; const int *dst;
    const float *Wa, *bA, *wt;
    const float *W0,*b0,*g0,*be0,*m0,*v0;
    const float *W1,*b1,*g1,*be1,*m1,*v1;
    const float *W2,*b2,*g2,*be2,*m2,*v2;
    const float *Wf,*bf;
    float *out;
    float *degA,*agg,*hAg,*scG;
    unsigned *gmaxU; float *gz; int *gkc; int *gec;
    int *keepSlot; float *kept0,*kept1,*degkG;
    int *aSG,*aDG;
    int N,E,G,P,epg;
};

// monotone float<->uint encoding so unsigned atomicMax == float max (bit-exact)
__device__ __forceinline__ unsigned encf(float f){
    unsigned b = __float_as_uint(f);
    return (b & 0x80000000u) ? ~b : (b | 0x80000000u);
}
__device__ __forceinline__ float decf(unsigned u){
    unsigned b = (u & 0x80000000u) ? (u & 0x7FFFFFFFu) : ~u;
    return __uint_as_float(b);
}

// ---------------------------------------------------------------------------
// Per-graph 3x(GCN+ReLU+BN) on kc kept rows + max-pool + head + log_softmax.
// Called by one 1024-thread block; shared buffers provided by caller.
// ---------------------------------------------------------------------------
__device__ void layers_head(const Prm& p, int g, int kc, int ec,
                            float* hbufL, float* tbufL, float* redM,
                            float* degkL, int* aSL, int* aDL,
                            float* pooledL, float* redA) {
    const int t = threadIdx.x;
    const int lane = t & 63, wid = t >> 6;
    const int c = t & (HDIM - 1);
    const int sub = t >> 7;
    const float* Ws[3]  = {p.W0,p.W1,p.W2};
    const float* bs[3]  = {p.b0,p.b1,p.b2};
    const float* gs[3]  = {p.g0,p.g1,p.g2};
    const float* bes[3] = {p.be0,p.be1,p.be2};
    const float* ms[3]  = {p.m0,p.m1,p.m2};
    const float* vs[3]  = {p.v0,p.v1,p.v2};

    for (int l = 0; l < 3; ++l) {
        const float* W = Ws[l];
        if (l == 0) {
            for (int r = sub; r < kc; r += 8)
                tbufL[r*HDIM+c] = hbufL[r*HDIM+0]*W[c] + hbufL[r*HDIM+1]*W[HDIM+c];
            __syncthreads();
        } else {
            for (int r = 0; r < kc; ++r) {
                float acc = 0.0f;
                const int k0 = sub * 16;
                #pragma unroll
                for (int i = 0; i < 16; ++i)
                    acc += hbufL[r*HDIM+k0+i] * W[(k0+i)*HDIM+c];
                redM[sub*HDIM+c] = acc;
                __syncthreads();
                if (t < HDIM) {
                    float s2 = 0.0f;
                    #pragma unroll
                    for (int q = 0; q < 8; ++q) s2 += redM[q*HDIM+c];
                    tbufL[r*HDIM+c] = s2;
                }
                __syncthreads();
            }
        }
        const float bb = bs[l][c];
        const float bscale = gs[l][c] * rsqrtf(vs[l][c] + EPSV);
        const float bmu = ms[l][c], bbe = bes[l][c];
        for (int r = sub; r < kc; r += 8) {
            float a = 0.0f;
            for (int e = 0; e < ec; ++e) {
                if (aDL[e] == r) {
                    int rs = aSL[e];
                    a += tbufL[rs*HDIM+c] * rsqrtf(degkL[rs]) * rsqrtf(degkL[r]);
                }
            }
            float v = a + tbufL[r*HDIM+c] * (1.0f/degkL[r]) + bb;
            v = fmaxf(v, 0.0f);
            hbufL[r*HDIM+c] = (v - bmu) * bscale + bbe;
        }
        __syncthreads();
    }

    if (t < HDIM) {
        float mm = -INFINITY;
        for (int r = 0; r < kc; ++r) mm = fmaxf(mm, hbufL[r*HDIM+t]);
        pooledL[t] = mm;
    }
    __syncthreads();

    if (wid < 3) {
        float acc = pooledL[lane]      * p.Wf[lane*3+wid] +
                    pooledL[lane + 64] * p.Wf[(lane+64)*3+wid];
        #pragma unroll
        for (int off = 32; off; off >>= 1) acc += __shfl_xor(acc, off);
        if (lane == 0) redA[wid] = acc + p.bf[wid];
    }
    __syncthreads();
    if (t == 0) {
        float l0 = redA[0], l1 = redA[1], l2 = redA[2];
        float mm = fmaxf(l0, fmaxf(l1, l2));
        float zs = expf(l0-mm) + expf(l1-mm) + expf(l2-mm);
        float lz = logf(zs) + mm;
        p.out[g*3+0] = l0 - lz;
        p.out[g*3+1] = l1 - lz;
        p.out[g*3+2] = l2 - lz;
    }
}

// ===========================================================================
// Cooperative single kernel: the whole pipeline, 7 grid syncs.
// ===========================================================================
__global__ __launch_bounds__(NT) void kcoop(Prm p) {
    cg::grid_group grid = cg::this_grid();
    const int tid = blockIdx.x * NT + threadIdx.x;
    const int nthr = NB * NT;
    const int N = p.N, E = p.E, G = p.G, Pn = p.P;
    const float2* __restrict__ x2 = (const float2*)p.x;

    // A: init workspace
    for (int i = tid; i < N; i += nthr) { p.degA[i]=0.f; p.agg[i]=0.f; p.keepSlot[i]=-1; }
    if (tid < GMAX) { p.gmaxU[tid]=0u; p.gz[tid]=0.f; p.gkc[tid]=0; p.gec[tid]=0; }
    for (int i = tid; i < G*KSEG; i += nthr) p.degkG[i] = 1.0f;
    grid.sync();

    // B: hA = x@Wa + in-degree scatter
    {
        const float wa0=p.Wa[0], wa1=p.Wa[1];
        for (int i = tid; i < N; i += nthr) { float2 xv=x2[i]; p.hAg[i]=xv.x*wa0+xv.y*wa1; }
        for (int e = tid; e < E; e += nthr) atomicAdd(&p.degA[p.dst[e]], 1.0f);
    }
    grid.sync();

    // C: normalized message scatter
    for (int e = tid; e < E; e += nthr) {
        int s = p.src[e], d = p.dst[e];
        float nrm = rsqrtf(1.f+p.degA[s]) * rsqrtf(1.f+p.degA[d]);
        atomicAdd(&p.agg[d], p.hAg[s]*nrm);
    }
    grid.sync();

    // D: score + per-graph max (wave pre-reduce, encoded atomicMax)
    {
        const float ba=p.bA[0], wtk=p.wt[0];
        const int nit = (N + nthr - 1) / nthr;
        for (int ib = 0; ib < nit; ++ib) {
            int i = tid + ib*nthr;
            bool v = i < N;
            float sc = 0.f; int g = -1;
            if (v) {
                float dg = 1.f + p.degA[i];
                sc = (p.agg[i] + p.hAg[i]*(1.f/dg) + ba) * wtk;
                p.scG[i] = sc;
                g = i / Pn;
            }
            unsigned enc = v ? encf(sc) : 0u;
            int ga = __shfl(g, 0), gb = __shfl(g, 63);
            if (ga == gb && ga >= 0) {
                unsigned r = enc;
                #pragma unroll
                for (int off = 32; off; off >>= 1) { unsigned o=__shfl_xor(r,off); r = o>r?o:r; }
                if ((threadIdx.x & 63) == 0) atomicMax(&p.gmaxU[ga], r);
            } else if (g >= 0) atomicMax(&p.gmaxU[g], enc);
        }
    }
    grid.sync();

    // E: z = sum exp(s - m)
    {
        const int nit = (N + nthr - 1) / nthr;
        for (int ib = 0; ib < nit; ++ib) {
            int i = tid + ib*nthr;
            bool v = i < N;
            float ex = 0.f; int g = -1;
            if (v) { g = i/Pn; ex = expf(p.scG[i] - decf(p.gmaxU[g])); }
            int ga = __shfl(g, 0), gb = __shfl(g, 63);
            if (ga == gb && ga >= 0) {
                float r = ex;
                #pragma unroll
                for (int off = 32; off; off >>= 1) r += __shfl_xor(r, off);
                if ((threadIdx.x & 63) == 0) atomicAdd(&p.gz[ga], r);
            } else if (g >= 0) atomicAdd(&p.gz[g], ex);
        }
    }
    grid.sync();

    // F: keep + compact (argmax has exp(0)=1 -> smax = 1/z, matches reference)
    for (int i = tid; i < N; i += nthr) {
        int g = i / Pn;
        float m = decf(p.gmaxU[g]), z = p.gz[g];
        float thr = fminf(1.f/z - TOLV, MINSCORE);
        float sc = expf(p.scG[i] - m) / z;
        if (sc > thr) {
            int k = atomicAdd(&p.gkc[g], 1);
            if (k < KSEG) {
                p.keepSlot[i] = k;
                float2 xv = x2[i];
                p.kept0[g*KSEG+k] = xv.x * sc;
                p.kept1[g*KSEG+k] = xv.y * sc;
            }
        }
    }
    grid.sync();

    // G: active edges (both kept) + kept-subgraph degree
    for (int e = tid; e < E; e += nthr) {
        int s = p.src[e], d = p.dst[e];
        int ks = p.keepSlot[s], kd = p.keepSlot[d];
        if (ks >= 0 && kd >= 0) {
            int g = d / Pn;
            int ep = atomicAdd(&p.gec[g], 1);
            if (ep < ESEG) { p.aSG[g*ESEG+ep] = ks; p.aDG[g*ESEG+ep] = kd; }
            atomicAdd(&p.degkG[g*KSEG+kd], 1.0f);
        }
    }
    grid.sync();

    // H: per-graph layer stack on blocks 0..G-1
    if ((int)blockIdx.x < G) {
        const int g = blockIdx.x, t = threadIdx.x;
        __shared__ float hbufL[KSEG*HDIM], tbufL[KSEG*HDIM], redM[8*HDIM];
        __shared__ float degkL[KSEG], pooledL[HDIM], redA[16];
        __shared__ int aSL[ESEG], aDL[ESEG];
        int kc = p.gkc[g]; if (kc > KSEG) kc = KSEG;
        int ec = p.gec[g]; if (ec > ESEG) ec = ESEG;
        if (t < KSEG && t < kc) {
            hbufL[t*HDIM+0] = p.kept0[g*KSEG+t];
            hbufL[t*HDIM+1] = p.kept1[g*KSEG+t];
            degkL[t] = p.degkG[g*KSEG+t];
        }
        if (t < ec) { aSL[t] = p.aSG[g*ESEG+t]; aDL[t] = p.aDG[g*ESEG+t]; }
        __syncthreads();
        layers_head(p, g, kc, ec, hbufL, tbufL, redM, degkL, aSL, aDL, pooledL, redA);
    }
}

// ===========================================================================
// Fallback path (no cooperative launch): zero + k1 + k2 + per-graph k3.
// ===========================================================================
__global__ __launch_bounds__(256) void k0z(Prm p) {
    int tid = blockIdx.x*256 + threadIdx.x, st = gridDim.x*256;
    for (int i = tid; i < 2*p.N; i += st) p.degA[i] = 0.f;   // degA|agg contiguous
}

__global__ __launch_bounds__(256) void k1f(Prm p) {
    int tid = blockIdx.x*256 + threadIdx.x, st = gridDim.x*256;
    const float wa0=p.Wa[0], wa1=p.Wa[1];
    const float2* x2 = (const float2*)p.x;
    for (int i = tid; i < p.N; i += st) { float2 xv=x2[i]; p.hAg[i]=xv.x*wa0+xv.y*wa1; }
    for (int e = tid; e < p.E; e += st) atomicAdd(&p.degA[p.dst[e]], 1.0f);
}

__global__ __launch_bounds__(256) void k2f(Prm p) {
    int tid = blockIdx.x*256 + threadIdx.x, st = gridDim.x*256;
    for (int e = tid; e < p.E; e += st) {
        int s = p.src[e], d = p.dst[e];
        float nrm = rsqrtf(1.f+p.degA[s]) * rsqrtf(1.f+p.degA[d]);
        atomicAdd(&p.agg[d], p.hAg[s]*nrm);
    }
}

__global__ __launch_bounds__(NT) void k3f(Prm p) {
    const int g = blockIdx.x, t = threadIdx.x;
    const int lane = t & 63, wid = t >> 6;
    const int base = g * p.P, e0 = g * p.epg, e1 = e0 + p.epg;
    __shared__ float scL[PMAX];
    __shared__ float hbufL[KSEG*HDIM], tbufL[KSEG*HDIM], redM[8*HDIM];
    __shared__ float redA[16], redB[16], mzS[2];
    __shared__ int keptL[KSEG];
    __shared__ float degkL[KSEG], pooledL[HDIM];
    __shared__ int aSL[ESEG], aDL[ESEG];
    __shared__ int kcnt, ecnt;

    if (t == 0) { kcnt = 0; ecnt = 0; }
    if (t < KSEG) degkL[t] = 1.0f;
    const float ba = p.bA[0], wtk = p.wt[0];
    const float2* x2 = (const float2*)p.x;

    float m = -INFINITY;
    for (int j = t; j < p.P; j += NT) {
        int i = base + j;
        float dg = 1.f + p.degA[i];
        float sc = (p.agg[i] + p.hAg[i]*(1.f/dg) + ba) * wtk;
        scL[j] = sc; m = fmaxf(m, sc);
    }
    #pragma unroll
    for (int off = 32; off; off >>= 1) m = fmaxf(m, __shfl_xor(m, off));
    if (lane == 0) redA[wid] = m;
    __syncthreads();
    if (wid == 0) {
        float v = (lane < 16) ? redA[lane] : -INFINITY;
        #pragma unroll
        for (int off = 8; off; off >>= 1) v = fmaxf(v, __shfl_xor(v, off));
        if (lane == 0) mzS[0] = v;
    }
    __syncthreads();
    m = mzS[0];

    float z = 0.0f;
    for (int j = t; j < p.P; j += NT) z += expf(scL[j] - m);
    #pragma unroll
    for (int off = 32; off; off >>= 1) z += __shfl_xor(z, off);
    if (lane == 0) redB[wid] = z;
    __syncthreads();
    if (wid == 0) {
        float v = (lane < 16) ? redB[lane] : 0.0f;
        #pragma unroll
        for (int off = 8; off; off >>= 1) v += __shfl_xor(v, off);
        if (lane == 0) mzS[1] = v;
    }
    __syncthreads();
    const float zz = mzS[1];
    const float thr = fminf(1.f/zz - TOLV, MINSCORE);

    for (int j = t; j < p.P; j += NT) {
        float sc = expf(scL[j] - m) / zz;
        if (sc > thr) {
            int k = atomicAdd(&kcnt, 1);
            if (k < KSEG) {
                keptL[k] = j;
                float2 xv = x2[base + j];
                hbufL[k*HDIM+0] = xv.x * sc;
                hbufL[k*HDIM+1] = xv.y * sc;
            }
        }
    }
    __syncthreads();
    const int kc = kcnt < KSEG ? kcnt : KSEG;

    for (int e = e0 + t; e < e1; e += NT) {
        int s = p.src[e] - base, d = p.dst[e] - base;
        int ks = -1, kd = -1;
        for (int q = 0; q < kc; ++q) {
            if (s == keptL[q]) ks = q;
            if (d == keptL[q]) kd = q;
        }
        if (ks >= 0 && kd >= 0) {
            int ee = atomicAdd(&ecnt, 1);
            if (ee < ESEG) { aSL[ee] = ks; aDL[ee] = kd; }
            atomicAdd(&degkL[kd], 1.0f);
        }
    }
    __syncthreads();
    const int ec = ecnt < ESEG ? ecnt : ESEG;

    layers_head(p, g, kc, ec, hbufL, tbufL, redM, degkL, aSL, aDL, pooledL, redA);
}

// ===========================================================================

extern "C" void kernel_launch(void* const* d_in, const int* in_sizes, int n_in,
                              void* d_out, int out_size, void* d_ws, size_t ws_size,
                              hipStream_t stream) {
    Prm prm;
    prm.x   = (const float*)d_in[0];
    prm.src = (const int*)d_in[1];
    prm.dst = (const int*)d_in[2];
    prm.Wa  = (const float*)d_in[5];
    prm.bA  = (const float*)d_in[6];
    prm.wt  = (const float*)d_in[7];
    prm.W0=(const float*)d_in[8];  prm.b0=(const float*)d_in[9];
    prm.g0=(const float*)d_in[10]; prm.be0=(const float*)d_in[11];
    prm.m0=(const float*)d_in[12]; prm.v0=(const float*)d_in[13];
    prm.W1=(const float*)d_in[14]; prm.b1=(const float*)d_in[15];
    prm.g1=(const float*)d_in[16]; prm.be1=(const float*)d_in[17];
    prm.m1=(const float*)d_in[18]; prm.v1=(const float*)d_in[19];
    prm.W2=(const float*)d_in[20]; prm.b2=(const float*)d_in[21];
    prm.g2=(const float*)d_in[22]; prm.be2=(const float*)d_in[23];
    prm.m2=(const float*)d_in[24]; prm.v2=(const float*)d_in[25];
    prm.Wf=(const float*)d_in[26]; prm.bf=(const float*)d_in[27];
    prm.out = (float*)d_out;

    prm.N = in_sizes[3];
    prm.E = in_sizes[1];
    prm.G = out_size / 3;
    prm.P = prm.N / prm.G;
    prm.epg = prm.E / prm.G;

    char* w = (char*)d_ws;
    auto alloc = [&](size_t bytes) -> void* {
        void* q = (void*)w;
        w += (bytes + 255) & ~size_t(255);
        return q;
    };
    prm.degA    = (float*)alloc((size_t)prm.N * 4);     // degA|agg contiguous (k0z)
    prm.agg     = (float*)alloc((size_t)prm.N * 4);
    prm.hAg     = (float*)alloc((size_t)prm.N * 4);
    prm.scG     = (float*)alloc((size_t)prm.N * 4);
    prm.keepSlot= (int*)alloc((size_t)prm.N * 4);
    prm.gmaxU   = (unsigned*)alloc(GMAX * 4);
    prm.gz      = (float*)alloc(GMAX * 4);
    prm.gkc     = (int*)alloc(GMAX * 4);
    prm.gec     = (int*)alloc(GMAX * 4);
    prm.kept0   = (float*)alloc(GMAX * KSEG * 4);
    prm.kept1   = (float*)alloc(GMAX * KSEG * 4);
    prm.degkG   = (float*)alloc(GMAX * KSEG * 4);
    prm.aSG     = (int*)alloc(GMAX * ESEG * 4);
    prm.aDG     = (int*)alloc(GMAX * ESEG * 4);

    void* kargs[] = { (void*)&prm };
    hipError_t err = hipLaunchCooperativeKernel((const void*)kcoop, dim3(NB), dim3(NT),
                                                kargs, 0, stream);
    if (err != hipSuccess) {
        (void)hipGetLastError();   // clear sticky error, use fallback path
        int nbE = (prm.E + 255) / 256;
        k0z<<<512, 256, 0, stream>>>(prm);
        k1f<<<nbE, 256, 0, stream>>>(prm);
        k2f<<<nbE, 256, 0, stream>>>(prm);
        k3f<<<prm.G, NT, 0, stream>>>(prm);
    }
}

// Round 7
// 73.274 us; speedup vs baseline: 3.6357x; 3.6357x over previous
//
#include <hip/hip_runtime.h>
#include <math.h>

#define HDIM 128
#define EPSV 1e-5f
#define TOLV 1e-7f
#define MINSCORE 0.1f
#define PMAX 2048
#define KSEG 16
#define ESEG 64
#define NT 1024

// ===========================================================================
// K0 (N-parallel): zero deg counters + hA = x @ W_attn
// ===========================================================================
__global__ __launch_bounds__(256) void k0(
        const float* __restrict__ x, const float* __restrict__ Wa,
        float* __restrict__ hA, unsigned* __restrict__ degI, int N) {
    const int tid = blockIdx.x * 256 + threadIdx.x;
    const int st = gridDim.x * 256;
    const float wa0 = Wa[0], wa1 = Wa[1];
    const float2* __restrict__ x2 = (const float2*)x;
    for (int i = tid; i < N; i += st) {
        float2 xv = x2[i];
        hA[i] = xv.x * wa0 + xv.y * wa1;
        degI[i] = 0u;
    }
}

// ===========================================================================
// K1 (E-parallel): in-degree histogram (u32 atomics) + zero agg (N-parallel)
// ===========================================================================
__global__ __launch_bounds__(256) void k1(
        const int* __restrict__ dst, unsigned* __restrict__ degI,
        float* __restrict__ agg, int N, int E) {
    const int tid = blockIdx.x * 256 + threadIdx.x;
    const int st = gridDim.x * 256;
    for (int i = tid; i < N; i += st) agg[i] = 0.0f;
    for (int e = tid; e < E; e += st) atomicAdd(&degI[dst[e]], 1u);
}

// ===========================================================================
// K2 (E-parallel): normalized message scatter via global f32 atomics.
// deg = 1 + count  (sums of 1.0f up to small counts are exact in f32).
// ===========================================================================
__global__ __launch_bounds__(256) void k2(
        const int* __restrict__ src, const int* __restrict__ dst,
        const float* __restrict__ hA, const unsigned* __restrict__ degI,
        float* __restrict__ agg, int E) {
    const int tid = blockIdx.x * 256 + threadIdx.x;
    const int st = gridDim.x * 256;
    for (int e = tid; e < E; e += st) {
        int s = src[e], d = dst[e];
        float nrm = rsqrtf(1.0f + (float)degI[s]) * rsqrtf(1.0f + (float)degI[d]);
        atomicAdd(&agg[d], hA[s] * nrm);
    }
}

// ===========================================================================
// K3: one block per graph. score -> shuffle softmax -> keep/compact ->
// edge membership scan -> 3x(GCN+ReLU+BN) on kept rows -> pool -> head.
// ===========================================================================
__global__ __launch_bounds__(NT) void k3(
        const float* __restrict__ x, const int* __restrict__ src,
        const int* __restrict__ dst, const float* __restrict__ hA,
        const unsigned* __restrict__ degI, const float* __restrict__ agg,
        const float* __restrict__ bA, const float* __restrict__ wt,
        const float* __restrict__ W0, const float* __restrict__ b0,
        const float* __restrict__ g0, const float* __restrict__ be0,
        const float* __restrict__ m0, const float* __restrict__ v0,
        const float* __restrict__ W1, const float* __restrict__ b1,
        const float* __restrict__ g1, const float* __restrict__ be1,
        const float* __restrict__ m1, const float* __restrict__ v1,
        const float* __restrict__ W2, const float* __restrict__ b2,
        const float* __restrict__ g2, const float* __restrict__ be2,
        const float* __restrict__ m2, const float* __restrict__ v2,
        const float* __restrict__ Wf, const float* __restrict__ bfv,
        float* __restrict__ out, int P, int epg) {
    const int g = blockIdx.x, t = threadIdx.x;
    const int lane = t & 63, wid = t >> 6;       // 16 waves
    const int base = g * P;
    const int e0 = g * epg, e1 = e0 + epg;

    __shared__ float scL[PMAX];
    __shared__ float hbufL[KSEG * HDIM], tbufL[KSEG * HDIM], redM[8 * HDIM];
    __shared__ float redA[16], redB[16], mzS[2];
    __shared__ int   keptL[KSEG];
    __shared__ float degkL[KSEG], pooledL[HDIM];
    __shared__ int   aSL[ESEG], aDL[ESEG];
    __shared__ int   kcnt, ecnt;

    if (t == 0) { kcnt = 0; ecnt = 0; }
    if (t < KSEG) degkL[t] = 1.0f;               // self-loop
    const float ba = bA[0], wtk = wt[0];
    const float2* __restrict__ x2 = (const float2*)x;

    // ---- score (coalesced) + max reduce ----
    float m = -INFINITY;
    for (int j = t; j < P; j += NT) {
        int i = base + j;
        float dg = 1.0f + (float)degI[i];
        float sc = (agg[i] + hA[i] * (1.0f / dg) + ba) * wtk;
        scL[j] = sc;
        m = fmaxf(m, sc);
    }
    #pragma unroll
    for (int off = 32; off; off >>= 1) m = fmaxf(m, __shfl_xor(m, off));
    if (lane == 0) redA[wid] = m;
    __syncthreads();
    if (wid == 0) {
        float v = (lane < 16) ? redA[lane] : -INFINITY;
        #pragma unroll
        for (int off = 8; off; off >>= 1) v = fmaxf(v, __shfl_xor(v, off));
        if (lane == 0) mzS[0] = v;
    }
    __syncthreads();
    m = mzS[0];

    // ---- z = sum exp(s - m) ----
    float z = 0.0f;
    for (int j = t; j < P; j += NT) z += expf(scL[j] - m);
    #pragma unroll
    for (int off = 32; off; off >>= 1) z += __shfl_xor(z, off);
    if (lane == 0) redB[wid] = z;
    __syncthreads();
    if (wid == 0) {
        float v = (lane < 16) ? redB[lane] : 0.0f;
        #pragma unroll
        for (int off = 8; off; off >>= 1) v += __shfl_xor(v, off);
        if (lane == 0) mzS[1] = v;
    }
    __syncthreads();
    const float zz = mzS[1];
    // argmax node has exp(0)=1 exactly -> smax = 1/zz (matches reference)
    const float thr = fminf(1.0f / zz - TOLV, MINSCORE);

    // ---- keep + compact; layer-0 rows h0 = x * score ----
    for (int j = t; j < P; j += NT) {
        float sc = expf(scL[j] - m) / zz;
        if (sc > thr) {
            int k = atomicAdd(&kcnt, 1);
            if (k < KSEG) {
                keptL[k] = j;
                float2 xv = x2[base + j];
                hbufL[k * HDIM + 0] = xv.x * sc;
                hbufL[k * HDIM + 1] = xv.y * sc;
            }
        }
    }
    __syncthreads();
    const int kc = kcnt < KSEG ? kcnt : KSEG;

    // ---- membership scan: edges with both endpoints kept ----
    for (int e = e0 + t; e < e1; e += NT) {
        int s = src[e] - base, d = dst[e] - base;
        int ks = -1, kd = -1;
        for (int q = 0; q < kc; ++q) {
            int kq = keptL[q];
            if (s == kq) ks = q;
            if (d == kq) kd = q;
        }
        if (ks >= 0 && kd >= 0) {
            int ee = atomicAdd(&ecnt, 1);
            if (ee < ESEG) { aSL[ee] = ks; aDL[ee] = kd; }
            atomicAdd(&degkL[kd], 1.0f);
        }
    }
    __syncthreads();
    const int ec = ecnt < ESEG ? ecnt : ESEG;

    // ---- 3 GCN layers on kc rows ----
    const int c   = t & (HDIM - 1);
    const int sub = t >> 7;                     // 0..7 split-K groups
    const float* Ws[3]  = {W0, W1, W2};
    const float* bs[3]  = {b0, b1, b2};
    const float* gs[3]  = {g0, g1, g2};
    const float* bes[3] = {be0, be1, be2};
    const float* ms[3]  = {m0, m1, m2};
    const float* vs[3]  = {v0, v1, v2};

    for (int l = 0; l < 3; ++l) {
        const float* W = Ws[l];
        if (l == 0) {
            for (int r = sub; r < kc; r += 8)
                tbufL[r*HDIM+c] = hbufL[r*HDIM+0]*W[c] + hbufL[r*HDIM+1]*W[HDIM+c];
            __syncthreads();
        } else {
            for (int r = 0; r < kc; ++r) {
                float acc = 0.0f;
                const int k0i = sub * 16;
                #pragma unroll
                for (int i = 0; i < 16; ++i)
                    acc += hbufL[r*HDIM+k0i+i] * W[(k0i+i)*HDIM+c];
                redM[sub*HDIM+c] = acc;
                __syncthreads();
                if (t < HDIM) {
                    float s2 = 0.0f;
                    #pragma unroll
                    for (int q = 0; q < 8; ++q) s2 += redM[q*HDIM+c];
                    tbufL[r*HDIM+c] = s2;
                }
                __syncthreads();
            }
        }
        const float bb = bs[l][c];
        const float bscale = gs[l][c] * rsqrtf(vs[l][c] + EPSV);
        const float bmu = ms[l][c], bbe = bes[l][c];
        for (int r = sub; r < kc; r += 8) {
            float a = 0.0f;
            for (int e = 0; e < ec; ++e) {
                if (aDL[e] == r) {
                    int rs = aSL[e];
                    a += tbufL[rs*HDIM+c] * rsqrtf(degkL[rs]) * rsqrtf(degkL[r]);
                }
            }
            float v = a + tbufL[r*HDIM+c] * (1.0f/degkL[r]) + bb;
            v = fmaxf(v, 0.0f);
            hbufL[r*HDIM+c] = (v - bmu) * bscale + bbe;
        }
        __syncthreads();
    }

    // ---- max-pool over kept rows ----
    if (t < HDIM) {
        float mm = -INFINITY;
        for (int r = 0; r < kc; ++r) mm = fmaxf(mm, hbufL[r*HDIM+t]);
        pooledL[t] = mm;
    }
    __syncthreads();

    // ---- head: wave r (r<3) computes logits[r] ----
    if (wid < 3) {
        float acc = pooledL[lane]      * Wf[lane*3+wid] +
                    pooledL[lane + 64] * Wf[(lane+64)*3+wid];
        #pragma unroll
        for (int off = 32; off; off >>= 1) acc += __shfl_xor(acc, off);
        if (lane == 0) redA[wid] = acc + bfv[wid];
    }
    __syncthreads();
    if (t == 0) {
        float l0 = redA[0], l1 = redA[1], l2 = redA[2];
        float mm = fmaxf(l0, fmaxf(l1, l2));
        float zs = expf(l0-mm) + expf(l1-mm) + expf(l2-mm);
        float lz = logf(zs) + mm;
        out[g*3+0] = l0 - lz;
        out[g*3+1] = l1 - lz;
        out[g*3+2] = l2 - lz;
    }
}

// ===========================================================================

extern "C" void kernel_launch(void* const* d_in, const int* in_sizes, int n_in,
                              void* d_out, int out_size, void* d_ws, size_t ws_size,
                              hipStream_t stream) {
    const float* x      = (const float*)d_in[0];
    const int*   src    = (const int*)d_in[1];
    const int*   dst    = (const int*)d_in[2];
    const float* W_attn = (const float*)d_in[5];
    const float* b_attn = (const float*)d_in[6];
    const float* w_topk = (const float*)d_in[7];
    float* out = (float*)d_out;

    int N  = in_sizes[3];
    int E  = in_sizes[1];
    int Gn = out_size / 3;
    int Pn = N / Gn;
    int epg = E / Gn;

    // workspace
    char* w = (char*)d_ws;
    auto alloc = [&](size_t bytes) -> void* {
        void* q = (void*)w;
        w += (bytes + 255) & ~size_t(255);
        return q;
    };
    unsigned* degI = (unsigned*)alloc((size_t)N * 4);
    float*    agg  = (float*)alloc((size_t)N * 4);
    float*    hA   = (float*)alloc((size_t)N * 4);

    int nbN = (N + 255) / 256;
    int nbE = (E + 255) / 256;

    k0<<<nbN, 256, 0, stream>>>(x, W_attn, hA, degI, N);
    k1<<<nbE, 256, 0, stream>>>(dst, degI, agg, N, E);
    k2<<<nbE, 256, 0, stream>>>(src, dst, hA, degI, agg, E);
    k3<<<Gn, NT, 0, stream>>>(x, src, dst, hA, degI, agg, b_attn, w_topk,
        (const float*)d_in[8],  (const float*)d_in[9],  (const float*)d_in[10],
        (const float*)d_in[11], (const float*)d_in[12], (const float*)d_in[13],
        (const float*)d_in[14], (const float*)d_in[15], (const float*)d_in[16],
        (const float*)d_in[17], (const float*)d_in[18], (const float*)d_in[19],
        (const float*)d_in[20], (const float*)d_in[21], (const float*)d_in[22],
        (const float*)d_in[23], (const float*)d_in[24], (const float*)d_in[25],
        (const float*)d_in[26], (const float*)d_in[27], out, Pn, epg);
}

// Round 8
// 47.554 us; speedup vs baseline: 5.6021x; 1.5409x over previous
//
#include <hip/hip_runtime.h>
#include <math.h>

#define HDIM 128
#define EPSV 1e-5f
#define TOLV 1e-7f
#define MINSCORE 0.1f
#define PMAX 2048
#define KSEG 16
#define ESEG 64
#define NT 1024
#define NSL 64          // edge slices per graph in D2

// ===========================================================================
// D1: one block per graph (block g -> XCD g%8). LDS in-degree histogram
// (no zeroed-global precondition), write degI, hA = x@Wa, zero agg.
// ===========================================================================
__global__ __launch_bounds__(NT) void d1(
        const float* __restrict__ x, const int* __restrict__ dst,
        const float* __restrict__ Wa, float* __restrict__ hA,
        unsigned* __restrict__ degI, float* __restrict__ agg, int P, int epg) {
    __shared__ unsigned degH[PMAX];
    const int g = blockIdx.x, t = threadIdx.x;
    const int base = g * P, e0 = g * epg, e1 = e0 + epg;
    for (int j = t; j < P; j += NT) degH[j] = 0u;
    __syncthreads();
    for (int e = e0 + t; e < e1; e += NT) {
        unsigned d = (unsigned)(dst[e] - base);
        if (d < (unsigned)P) atomicAdd(&degH[d], 1u);
    }
    __syncthreads();
    const float wa0 = Wa[0], wa1 = Wa[1];
    const float2* __restrict__ x2 = (const float2*)x;
    for (int j = t; j < P; j += NT) {
        int i = base + j;
        float2 xv = x2[i];
        hA[i]   = xv.x * wa0 + xv.y * wa1;
        degI[i] = degH[j];
        agg[i]  = 0.0f;
    }
}

// ===========================================================================
// D2: E-parallel normalized message scatter. Blocks are swizzled so ALL
// blocks of graph g run on XCD g%8 -> agg atomics stay in one L2.
// ===========================================================================
__global__ __launch_bounds__(256) void d2(
        const int* __restrict__ src, const int* __restrict__ dst,
        const float* __restrict__ hA, const unsigned* __restrict__ degI,
        float* __restrict__ agg, int P, int epg, int eps, int qpx) {
    const int b = blockIdx.x;
    int g, sl;
    if (qpx > 0) {              // XCD-aligned mapping (requires G % 8 == 0)
        int c = b & 7, j = b >> 3;
        g = c + 8 * (j % qpx);
        sl = j / qpx;
    } else {                    // fallback: plain mapping
        g = b / NSL; sl = b - g * NSL;
    }
    const int e0 = g * epg + sl * eps;
    int e1 = e0 + eps; int eg = g * epg + epg; if (e1 > eg) e1 = eg;
    for (int e = e0 + threadIdx.x; e < e1; e += 256) {
        int s = src[e], d = dst[e];
        float nrm = rsqrtf(1.0f + (float)degI[s]) * rsqrtf(1.0f + (float)degI[d]);
        atomicAdd(&agg[d], hA[s] * nrm);
    }
}

// ===========================================================================
// D3: one block per graph (block g -> XCD g%8, same L2 as D1/D2 writes).
// score -> shuffle softmax -> keep/compact -> [membership scan ONLY if kc>1]
// -> 3x(GCN+ReLU+BN) -> pool -> head -> log_softmax.
// kc==1 algebra: active edges are self-edges; agg + self = t exactly.
// ===========================================================================
__global__ __launch_bounds__(NT) void d3(
        const float* __restrict__ x, const int* __restrict__ src,
        const int* __restrict__ dst, const float* __restrict__ hA,
        const unsigned* __restrict__ degI, const float* __restrict__ agg,
        const float* __restrict__ bA, const float* __restrict__ wt,
        const float* __restrict__ W0, const float* __restrict__ b0,
        const float* __restrict__ g0, const float* __restrict__ be0,
        const float* __restrict__ m0, const float* __restrict__ v0,
        const float* __restrict__ W1, const float* __restrict__ b1,
        const float* __restrict__ g1, const float* __restrict__ be1,
        const float* __restrict__ m1, const float* __restrict__ v1,
        const float* __restrict__ W2, const float* __restrict__ b2,
        const float* __restrict__ g2, const float* __restrict__ be2,
        const float* __restrict__ m2, const float* __restrict__ v2,
        const float* __restrict__ Wf, const float* __restrict__ bfv,
        float* __restrict__ out, int P, int epg) {
    const int g = blockIdx.x, t = threadIdx.x;
    const int lane = t & 63, wid = t >> 6;       // 16 waves
    const int base = g * P;
    const int e0 = g * epg, e1 = e0 + epg;

    __shared__ float scL[PMAX];
    __shared__ float hbufL[KSEG * HDIM], tbufL[KSEG * HDIM], redM[8 * HDIM];
    __shared__ float redA[16], redB[16], mzS[2];
    __shared__ int   keptL[KSEG];
    __shared__ float degkL[KSEG], pooledL[HDIM];
    __shared__ int   aSL[ESEG], aDL[ESEG];
    __shared__ int   kcnt, ecnt;

    if (t == 0) { kcnt = 0; ecnt = 0; }
    if (t < KSEG) degkL[t] = 1.0f;               // self-loop
    const float ba = bA[0], wtk = wt[0];
    const float2* __restrict__ x2 = (const float2*)x;

    // ---- score (coalesced; L2-resident from D1/D2) + max reduce ----
    float m = -INFINITY;
    for (int j = t; j < P; j += NT) {
        int i = base + j;
        float dg = 1.0f + (float)degI[i];
        float sc = (agg[i] + hA[i] * (1.0f / dg) + ba) * wtk;
        scL[j] = sc;
        m = fmaxf(m, sc);
    }
    #pragma unroll
    for (int off = 32; off; off >>= 1) m = fmaxf(m, __shfl_xor(m, off));
    if (lane == 0) redA[wid] = m;
    __syncthreads();
    if (wid == 0) {
        float v = (lane < 16) ? redA[lane] : -INFINITY;
        #pragma unroll
        for (int off = 8; off; off >>= 1) v = fmaxf(v, __shfl_xor(v, off));
        if (lane == 0) mzS[0] = v;
    }
    __syncthreads();
    m = mzS[0];

    // ---- z = sum exp(s - m) ----
    float z = 0.0f;
    for (int j = t; j < P; j += NT) z += expf(scL[j] - m);
    #pragma unroll
    for (int off = 32; off; off >>= 1) z += __shfl_xor(z, off);
    if (lane == 0) redB[wid] = z;
    __syncthreads();
    if (wid == 0) {
        float v = (lane < 16) ? redB[lane] : 0.0f;
        #pragma unroll
        for (int off = 8; off; off >>= 1) v += __shfl_xor(v, off);
        if (lane == 0) mzS[1] = v;
    }
    __syncthreads();
    const float zz = mzS[1];
    // argmax node has exp(0)=1 exactly -> smax = 1/zz (matches reference)
    const float thr = fminf(1.0f / zz - TOLV, MINSCORE);

    // ---- keep + compact; layer-0 rows h0 = x * score ----
    for (int j = t; j < P; j += NT) {
        float sc = expf(scL[j] - m) / zz;
        if (sc > thr) {
            int k = atomicAdd(&kcnt, 1);
            if (k < KSEG) {
                keptL[k] = j;
                float2 xv = x2[base + j];
                hbufL[k * HDIM + 0] = xv.x * sc;
                hbufL[k * HDIM + 1] = xv.y * sc;
            }
        }
    }
    __syncthreads();
    const int kc = kcnt < KSEG ? kcnt : KSEG;

    // ---- membership scan ONLY if more than one node kept ----
    int ec = 0;
    if (kc > 1) {
        for (int e = e0 + t; e < e1; e += NT) {
            int s = src[e] - base, d = dst[e] - base;
            int ks = -1, kd = -1;
            for (int q = 0; q < kc; ++q) {
                int kq = keptL[q];
                if (s == kq) ks = q;
                if (d == kq) kd = q;
            }
            if (ks >= 0 && kd >= 0) {
                int ee = atomicAdd(&ecnt, 1);
                if (ee < ESEG) { aSL[ee] = ks; aDL[ee] = kd; }
                atomicAdd(&degkL[kd], 1.0f);
            }
        }
        __syncthreads();
        ec = ecnt < ESEG ? ecnt : ESEG;
    }

    // ---- 3 GCN layers on kc rows ----
    const int c   = t & (HDIM - 1);
    const int sub = t >> 7;                     // 0..7 split-K groups
    const float* Ws[3]  = {W0, W1, W2};
    const float* bs[3]  = {b0, b1, b2};
    const float* gs[3]  = {g0, g1, g2};
    const float* bes[3] = {be0, be1, be2};
    const float* ms[3]  = {m0, m1, m2};
    const float* vs[3]  = {v0, v1, v2};

    for (int l = 0; l < 3; ++l) {
        const float* W = Ws[l];
        if (l == 0) {
            for (int r = sub; r < kc; r += 8)
                tbufL[r*HDIM+c] = hbufL[r*HDIM+0]*W[c] + hbufL[r*HDIM+1]*W[HDIM+c];
            __syncthreads();
        } else {
            for (int r = 0; r < kc; ++r) {
                float acc = 0.0f;
                const int k0i = sub * 16;
                #pragma unroll
                for (int i = 0; i < 16; ++i)
                    acc += hbufL[r*HDIM+k0i+i] * W[(k0i+i)*HDIM+c];
                redM[sub*HDIM+c] = acc;
                __syncthreads();
                if (t < HDIM) {
                    float s2 = 0.0f;
                    #pragma unroll
                    for (int q = 0; q < 8; ++q) s2 += redM[q*HDIM+c];
                    tbufL[r*HDIM+c] = s2;
                }
                __syncthreads();
            }
        }
        const float bb = bs[l][c];
        const float bscale = gs[l][c] * rsqrtf(vs[l][c] + EPSV);
        const float bmu = ms[l][c], bbe = bes[l][c];
        if (kc == 1) {
            // agg + self term == t exactly (all active edges are self-edges)
            if (t < HDIM) {
                float v = tbufL[c] + bb;
                v = fmaxf(v, 0.0f);
                hbufL[c] = (v - bmu) * bscale + bbe;
            }
            __syncthreads();
        } else {
            for (int r = sub; r < kc; r += 8) {
                float a = 0.0f;
                for (int e = 0; e < ec; ++e) {
                    if (aDL[e] == r) {
                        int rs = aSL[e];
                        a += tbufL[rs*HDIM+c] * rsqrtf(degkL[rs]) * rsqrtf(degkL[r]);
                    }
                }
                float v = a + tbufL[r*HDIM+c] * (1.0f/degkL[r]) + bb;
                v = fmaxf(v, 0.0f);
                hbufL[r*HDIM+c] = (v - bmu) * bscale + bbe;
            }
            __syncthreads();
        }
    }

    // ---- max-pool over kept rows ----
    if (t < HDIM) {
        float mm = -INFINITY;
        for (int r = 0; r < kc; ++r) mm = fmaxf(mm, hbufL[r*HDIM+t]);
        pooledL[t] = mm;
    }
    __syncthreads();

    // ---- head: wave r (r<3) computes logits[r] ----
    if (wid < 3) {
        float acc = pooledL[lane]      * Wf[lane*3+wid] +
                    pooledL[lane + 64] * Wf[(lane+64)*3+wid];
        #pragma unroll
        for (int off = 32; off; off >>= 1) acc += __shfl_xor(acc, off);
        if (lane == 0) redA[wid] = acc + bfv[wid];
    }
    __syncthreads();
    if (t == 0) {
        float l0 = redA[0], l1 = redA[1], l2 = redA[2];
        float mm = fmaxf(l0, fmaxf(l1, l2));
        float zs = expf(l0-mm) + expf(l1-mm) + expf(l2-mm);
        float lz = logf(zs) + mm;
        out[g*3+0] = l0 - lz;
        out[g*3+1] = l1 - lz;
        out[g*3+2] = l2 - lz;
    }
}

// ===========================================================================

extern "C" void kernel_launch(void* const* d_in, const int* in_sizes, int n_in,
                              void* d_out, int out_size, void* d_ws, size_t ws_size,
                              hipStream_t stream) {
    const float* x      = (const float*)d_in[0];
    const int*   src    = (const int*)d_in[1];
    const int*   dst    = (const int*)d_in[2];
    const float* W_attn = (const float*)d_in[5];
    const float* b_attn = (const float*)d_in[6];
    const float* w_topk = (const float*)d_in[7];
    float* out = (float*)d_out;

    int N  = in_sizes[3];
    int E  = in_sizes[1];
    int Gn = out_size / 3;
    int Pn = N / Gn;
    int epg = E / Gn;

    // workspace
    char* w = (char*)d_ws;
    auto alloc = [&](size_t bytes) -> void* {
        void* q = (void*)w;
        w += (bytes + 255) & ~size_t(255);
        return q;
    };
    unsigned* degI = (unsigned*)alloc((size_t)N * 4);
    float*    agg  = (float*)alloc((size_t)N * 4);
    float*    hA   = (float*)alloc((size_t)N * 4);

    int eps = (epg + NSL - 1) / NSL;            // edges per slice
    int qpx = (Gn % 8 == 0) ? Gn / 8 : 0;       // graphs per XCD (swizzle on)

    d1<<<Gn, NT, 0, stream>>>(x, dst, W_attn, hA, degI, agg, Pn, epg);
    d2<<<Gn * NSL, 256, 0, stream>>>(src, dst, hA, degI, agg, Pn, epg, eps, qpx);
    d3<<<Gn, NT, 0, stream>>>(x, src, dst, hA, degI, agg, b_attn, w_topk,
        (const float*)d_in[8],  (const float*)d_in[9],  (const float*)d_in[10],
        (const float*)d_in[11], (const float*)d_in[12], (const float*)d_in[13],
        (const float*)d_in[14], (const float*)d_in[15], (const float*)d_in[16],
        (const float*)d_in[17], (const float*)d_in[18], (const float*)d_in[19],
        (const float*)d_in[20], (const float*)d_in[21], (const float*)d_in[22],
        (const float*)d_in[23], (const float*)d_in[24], (const float*)d_in[25],
        (const float*)d_in[26], (const float*)d_in[27], out, Pn, epg);
}